// Round 2
// baseline (449.974 us; speedup 1.0000x reference)
//
#include <hip/hip_runtime.h>

// ---------------------------------------------------------------------------
// GCN pipeline:
//   deg histogram -> exclusive scan (CSR offsets) -> edge placement (sort by dst)
//   -> transform1 (x@W1, pre-scaled by dinv) -> gather-aggregate (64 feat)
//   -> transform2 -> gather-aggregate (32 feat) -> fused FC head
// ---------------------------------------------------------------------------

__global__ void count_deg(const int* __restrict__ dst, int* __restrict__ deg, int E) {
    int e = blockIdx.x * blockDim.x + threadIdx.x;
    if (e < E) atomicAdd(&deg[dst[e]], 1);
}

// Exclusive scan, tile = 2048 elems (256 thr x 8 items)
__global__ void scanA(const int* __restrict__ deg, int* __restrict__ offs,
                      int* __restrict__ bsums, int n) {
    __shared__ int lds[256];
    int t = threadIdx.x;
    int base = blockIdx.x * 2048 + t * 8;
    int v[8];
    int sum = 0;
#pragma unroll
    for (int j = 0; j < 8; ++j) {
        int i = base + j;
        v[j] = (i < n) ? deg[i] : 0;
        sum += v[j];
    }
    lds[t] = sum;
    __syncthreads();
    int incl = sum;
    for (int d = 1; d < 256; d <<= 1) {
        int add = (t >= d) ? lds[t - d] : 0;
        __syncthreads();
        incl += add;
        lds[t] = incl;
        __syncthreads();
    }
    int run = incl - sum;  // exclusive for this thread
#pragma unroll
    for (int j = 0; j < 8; ++j) {
        int i = base + j;
        if (i < n) offs[i] = run;
        run += v[j];
    }
    if (t == 255) bsums[blockIdx.x] = incl;  // block total
}

// Scan of block sums (nb <= 64) with a single wave
__global__ void scanB(int* __restrict__ bsums, int nb) {
    int l = threadIdx.x;
    int v = (l < nb) ? bsums[l] : 0;
    int incl = v;
#pragma unroll
    for (int d = 1; d < 64; d <<= 1) {
        int up = __shfl_up(incl, d, 64);
        if (l >= d) incl += up;
    }
    if (l < nb) bsums[l] = incl - v;
}

__global__ void scanC(int* __restrict__ offs, const int* __restrict__ bsums,
                      int* __restrict__ cursor, const int* __restrict__ deg,
                      float* __restrict__ dinv, int n) {
    int i = blockIdx.x * blockDim.x + threadIdx.x;
    if (i < n) {
        int off = offs[i] + bsums[i >> 11];
        offs[i] = off;
        cursor[i] = off;
        dinv[i] = 1.0f / sqrtf((float)(deg[i] + 1));  // +1 self loop
    }
}

__global__ void place_edges(const int* __restrict__ src, const int* __restrict__ dst,
                            int* __restrict__ cursor, int* __restrict__ srcs, int E) {
    int e = blockIdx.x * blockDim.x + threadIdx.x;
    if (e < E) {
        int p = atomicAdd(&cursor[dst[e]], 1);
        srcs[p] = src[e];
    }
}

// h1'[i,f] = dinv[i] * sum_k x[i,k]*W1[k,f]   (x: [n,5], W1: [5,64])
__global__ void transform1(const float* __restrict__ x, const float* __restrict__ W1,
                           const float* __restrict__ dinv, float* __restrict__ h, int n) {
    __shared__ float w[320];
    int t = threadIdx.x;
    w[t] = W1[t];
    if (t < 64) w[t + 256] = W1[t + 256];
    __syncthreads();
    int idx = blockIdx.x * 256 + t;
    int i = idx >> 6, f = idx & 63;
    if (i < n) {
        float acc = 0.f;
#pragma unroll
        for (int k = 0; k < 5; ++k) acc += x[i * 5 + k] * w[k * 64 + f];
        h[idx] = acc * dinv[i];
    }
}

// out[i,f] = relu(dinv[i]*(h'[i,f] + sum_{e:dst=i} h'[src,f]) + b[f])
template <int F>
__global__ void aggregate(const float* __restrict__ h, const int* __restrict__ srcs,
                          const int* __restrict__ offs, const int* __restrict__ deg,
                          const float* __restrict__ dinv, const float* __restrict__ bias,
                          float* __restrict__ out, int n) {
    int idx = blockIdx.x * blockDim.x + threadIdx.x;
    int i = idx / F, f = idx % F;
    if (i >= n) return;
    float acc = h[(size_t)i * F + f];  // self-loop term (pre-scaled)
    int off = offs[i], cnt = deg[i];
    int p = 0;
    for (; p + 4 <= cnt; p += 4) {
        int s0 = srcs[off + p + 0];
        int s1 = srcs[off + p + 1];
        int s2 = srcs[off + p + 2];
        int s3 = srcs[off + p + 3];
        float a0 = h[(size_t)s0 * F + f];
        float a1 = h[(size_t)s1 * F + f];
        float a2 = h[(size_t)s2 * F + f];
        float a3 = h[(size_t)s3 * F + f];
        acc += a0 + a1 + a2 + a3;
    }
    for (; p < cnt; ++p) acc += h[(size_t)srcs[off + p] * F + f];
    float v = dinv[i] * acc + bias[f];
    out[idx] = fmaxf(v, 0.0f);
}

// h2'[i,g] = dinv[i] * sum_k x1[i,k]*W2[k,g]   (x1: [n,64], W2: [64,32])
__global__ void transform2(const float* __restrict__ x1, const float* __restrict__ W2,
                           const float* __restrict__ dinv, float* __restrict__ h2, int n) {
    __shared__ float ws[64 * 32];
    __shared__ float xs[8 * 64];
    int t = threadIdx.x;
#pragma unroll
    for (int k = 0; k < 8; ++k) ws[t + k * 256] = W2[t + k * 256];
    int blockNode = blockIdx.x * 8;
    int g0 = blockNode * 64;
    if (g0 + t < n * 64) xs[t] = x1[g0 + t];
    if (g0 + 256 + t < n * 64) xs[t + 256] = x1[g0 + 256 + t];
    __syncthreads();
    int li = t >> 5, g = t & 31;
    int i = blockNode + li;
    if (i >= n) return;
    float acc = 0.f;
#pragma unroll
    for (int k = 0; k < 64; ++k) acc += xs[li * 64 + k] * ws[k * 32 + g];
    h2[(size_t)i * 32 + g] = acc * dinv[i];
}

// x3 = relu(x2@fcW1 + fcb1); out = x3@fcW2 + fcb2   (per-node thread)
__global__ void fc_head(const float* __restrict__ x2, const float* __restrict__ fcW1,
                        const float* __restrict__ fcb1, const float* __restrict__ fcW2,
                        const float* __restrict__ fcb2, float* __restrict__ out, int n) {
    __shared__ float w1s[512];
    __shared__ float w2s[32];
    __shared__ float b1s[16];
    __shared__ float b2s[2];
    int t = threadIdx.x;
    w1s[t] = fcW1[t];
    w1s[t + 256] = fcW1[t + 256];
    if (t < 32) w2s[t] = fcW2[t];
    if (t < 16) b1s[t] = fcb1[t];
    if (t < 2) b2s[t] = fcb2[t];
    __syncthreads();
    int i = blockIdx.x * 256 + t;
    if (i >= n) return;
    float r[32];
    const float4* xv = (const float4*)(x2 + (size_t)i * 32);
#pragma unroll
    for (int q = 0; q < 8; ++q) {
        float4 v = xv[q];
        r[4 * q + 0] = v.x; r[4 * q + 1] = v.y;
        r[4 * q + 2] = v.z; r[4 * q + 3] = v.w;
    }
    float x3[16];
#pragma unroll
    for (int j = 0; j < 16; ++j) {
        float a = b1s[j];
#pragma unroll
        for (int k = 0; k < 32; ++k) a += r[k] * w1s[k * 16 + j];
        x3[j] = fmaxf(a, 0.f);
    }
#pragma unroll
    for (int o = 0; o < 2; ++o) {
        float a = b2s[o];
#pragma unroll
        for (int j = 0; j < 16; ++j) a += x3[j] * w2s[j * 2 + o];
        out[(size_t)i * 2 + o] = a;
    }
}

extern "C" void kernel_launch(void* const* d_in, const int* in_sizes, int n_in,
                              void* d_out, int out_size, void* d_ws, size_t ws_size,
                              hipStream_t stream) {
    const float* edge_attr = (const float*)d_in[0];
    const int* edge_index  = (const int*)d_in[1];
    const float* W1   = (const float*)d_in[2];
    const float* b1   = (const float*)d_in[3];
    const float* W2   = (const float*)d_in[4];
    const float* b2   = (const float*)d_in[5];
    const float* fcW1 = (const float*)d_in[6];
    const float* fcb1 = (const float*)d_in[7];
    const float* fcW2 = (const float*)d_in[8];
    const float* fcb2 = (const float*)d_in[9];
    float* out = (float*)d_out;

    int n = in_sizes[0] / 5;
    int E = in_sizes[1] / 2;
    const int* src = edge_index;
    const int* dst = edge_index + E;

    char* ws = (char*)d_ws;
    auto alloc = [&](size_t bytes) {
        char* p = ws;
        ws += (bytes + 255) & ~(size_t)255;
        return p;
    };
    int*   deg    = (int*)alloc((size_t)n * 4);
    int*   offs   = (int*)alloc((size_t)n * 4);
    int*   cursor = (int*)alloc((size_t)n * 4);
    float* dinv   = (float*)alloc((size_t)n * 4);
    int*   bsums  = (int*)alloc(4096);
    int*   srcs   = (int*)alloc((size_t)E * 4);
    float* bufA   = (float*)alloc((size_t)n * 64 * 4);
    float* bufB   = (float*)alloc((size_t)n * 64 * 4);

    hipMemsetAsync(deg, 0, (size_t)n * sizeof(int), stream);

    int eb = (E + 255) / 256;
    count_deg<<<eb, 256, 0, stream>>>(dst, deg, E);

    int nScanBlocks = (n + 2047) / 2048;  // 49 for n=100000 (must be <= 64)
    scanA<<<nScanBlocks, 256, 0, stream>>>(deg, offs, bsums, n);
    scanB<<<1, 64, 0, stream>>>(bsums, nScanBlocks);
    scanC<<<(n + 255) / 256, 256, 0, stream>>>(offs, bsums, cursor, deg, dinv, n);
    place_edges<<<eb, 256, 0, stream>>>(src, dst, cursor, srcs, E);

    transform1<<<(n * 64 + 255) / 256, 256, 0, stream>>>(edge_attr, W1, dinv, bufA, n);
    aggregate<64><<<(n * 64 + 255) / 256, 256, 0, stream>>>(bufA, srcs, offs, deg, dinv,
                                                            b1, bufB, n);
    transform2<<<(n + 7) / 8, 256, 0, stream>>>(bufB, W2, dinv, bufA, n);
    aggregate<32><<<(n * 32 + 255) / 256, 256, 0, stream>>>(bufA, srcs, offs, deg, dinv,
                                                            b2, bufB, n);
    fc_head<<<(n + 255) / 256, 256, 0, stream>>>(bufB, fcW1, fcb1, fcW2, fcb2, out, n);
}